// Round 2
// baseline (2001.228 us; speedup 1.0000x reference)
//
#include <hip/hip_runtime.h>
#include <math.h>

// Problem constants
constexpr int NB = 32, HH = 32, WW = 32, CD = 256, NK = 4096;
constexpr int T_ = NB * WW * HH;                       // 32768 tokens
constexpr long long NQ = (long long)NB * CD * HH * WW; // 8388608
constexpr long long OFF_LOSS = NQ;
constexpr long long OFF_PERP = NQ + 1;
constexpr long long OFF_ENC  = NQ + 2;                    // 8388610
constexpr long long ENC_SZ   = (long long)T_ * NK;        // 134217728
constexpr long long OFF_IDX  = OFF_ENC + ENC_SZ;          // 142606338
constexpr long long OFF_DIST = OFF_IDX + T_;              // 142639106
// scratch inside encodings output region (dead before k_onehot overwrites it)
constexpr long long SCR_FLAT = OFF_ENC + 2;               // 16B-aligned
constexpr long long SCR_PVAL = SCR_FLAT + (long long)T_ * CD;
constexpr long long SCR_PIDX = SCR_PVAL + (long long)T_ * 32;

#define TID ((int)threadIdx.x)

// ---- NCHW -> [T, C] transpose (both sides coalesced via LDS) ----
__global__ __launch_bounds__(256) void k_transpose(const float* __restrict__ in,
                                                   float* __restrict__ flat) {
  __shared__ float t[256][33];
  int b = blockIdx.x, n = b >> 5, h = b & 31;
  int w = TID & 31, c8 = TID >> 5;
  const float* src = in + (long long)n * 262144 + h * 32;  // + c*1024 + w
#pragma unroll
  for (int p = 0; p < 32; ++p) {
    int c = p * 8 + c8;
    t[c][w] = src[c * 1024 + w];
  }
  __syncthreads();
  float* dst = flat + ((long long)n * 1024 + h) * 256;     // + w*8192 + c
#pragma unroll
  for (int w2 = 0; w2 < 32; ++w2) dst[w2 * 8192 + TID] = t[TID][w2];
}

// ---- per-row squared L2 norm (one wave per row) ----
__global__ __launch_bounds__(256) void k_rowsq(const float* __restrict__ src,
                                               float* __restrict__ dst, int nrows) {
  int row = blockIdx.x * 4 + (TID >> 6);
  if (row >= nrows) return;
  int lane = TID & 63;
  float4 v = *(const float4*)(src + (long long)row * 256 + lane * 4);
  float s = v.x * v.x + v.y * v.y + v.z * v.z + v.w * v.w;
#pragma unroll
  for (int o = 32; o; o >>= 1) s += __shfl_down(s, o);
  if (lane == 0) dst[row] = s;
}

// ---- fp32 distance GEMM: 128x128 tile, BK=16, 8x8 micro-tile, fused argmin ----
// Named float4 accumulators (no runtime-indexed arrays -> stay in VGPRs).
#define MK(ci0, ci1, aa)                                          \
  ci0.x = fmaf(aa, B0.x, ci0.x); ci0.y = fmaf(aa, B0.y, ci0.y);   \
  ci0.z = fmaf(aa, B0.z, ci0.z); ci0.w = fmaf(aa, B0.w, ci0.w);   \
  ci1.x = fmaf(aa, B1.x, ci1.x); ci1.y = fmaf(aa, B1.y, ci1.y);   \
  ci1.z = fmaf(aa, B1.z, ci1.z); ci1.w = fmaf(aa, B1.w, ci1.w);

#define EPI(hh_, ii_, C0, C1) {                                                 \
  int row = bm * 128 + (hh_) * 64 + tm * 4 + (ii_);                             \
  float xs = xsq[row];                                                          \
  float4 dv0, dv1;                                                              \
  dv0.x = xs - 2.0f * C0.x + ep0.x; dv0.y = xs - 2.0f * C0.y + ep0.y;           \
  dv0.z = xs - 2.0f * C0.z + ep0.z; dv0.w = xs - 2.0f * C0.w + ep0.w;           \
  dv1.x = xs - 2.0f * C1.x + ep1.x; dv1.y = xs - 2.0f * C1.y + ep1.y;           \
  dv1.z = xs - 2.0f * C1.z + ep1.z; dv1.w = xs - 2.0f * C1.w + ep1.w;           \
  float bv = dv0.x; int bc = tn * 4;                                            \
  if (dv0.y < bv) { bv = dv0.y; bc = tn * 4 + 1; }                              \
  if (dv0.z < bv) { bv = dv0.z; bc = tn * 4 + 2; }                              \
  if (dv0.w < bv) { bv = dv0.w; bc = tn * 4 + 3; }                              \
  if (dv1.x < bv) { bv = dv1.x; bc = 64 + tn * 4; }                             \
  if (dv1.y < bv) { bv = dv1.y; bc = 64 + tn * 4 + 1; }                         \
  if (dv1.z < bv) { bv = dv1.z; bc = 64 + tn * 4 + 2; }                         \
  if (dv1.w < bv) { bv = dv1.w; bc = 64 + tn * 4 + 3; }                         \
  float* drow = dist + (long long)row * 4096 + bn * 128;                        \
  *(float4*)(drow + tn * 4) = dv0;                                              \
  *(float4*)(drow + 64 + tn * 4) = dv1;                                         \
  _Pragma("unroll")                                                             \
  for (int m_ = 1; m_ < 16; m_ <<= 1) {                                         \
    float ov = __shfl_xor(bv, m_); int oc = __shfl_xor(bc, m_);                 \
    if (ov < bv || (ov == bv && oc < bc)) { bv = ov; bc = oc; }                 \
  }                                                                             \
  if (tn == 0) {                                                                \
    pval[(long long)bn * 32768 + row] = bv;                                     \
    pidx[(long long)bn * 32768 + row] = bn * 128 + bc;                          \
  }                                                                             \
}

__global__ __launch_bounds__(256, 2) void k_gemm(const float* __restrict__ A,
                                                 const float* __restrict__ B,
                                                 const float* __restrict__ xsq,
                                                 const float* __restrict__ esq,
                                                 float* __restrict__ dist,
                                                 float* __restrict__ pval,
                                                 int* __restrict__ pidx) {
  __shared__ float4 As4[16][33];  // [k][m/4], pad
  __shared__ float4 Bs4[16][33];
  float* As_s = (float*)As4;
  float* Bs_s = (float*)Bs4;
  int tid = TID;
  int bm = blockIdx.x >> 5, bn = blockIdx.x & 31;
  int tn = tid & 15, tm = tid >> 4;
  int lr = tid >> 2, lk = tid & 3;
  const float* Ag = A + (long long)bm * 128 * 256 + lr * 256 + lk * 4;
  const float* Bg = B + (long long)bn * 128 * 256 + lr * 256 + lk * 4;

  float4 c000 = {0,0,0,0}, c001 = {0,0,0,0}, c010 = {0,0,0,0}, c011 = {0,0,0,0};
  float4 c020 = {0,0,0,0}, c021 = {0,0,0,0}, c030 = {0,0,0,0}, c031 = {0,0,0,0};
  float4 c100 = {0,0,0,0}, c101 = {0,0,0,0}, c110 = {0,0,0,0}, c111 = {0,0,0,0};
  float4 c120 = {0,0,0,0}, c121 = {0,0,0,0}, c130 = {0,0,0,0}, c131 = {0,0,0,0};

  float4 pa0 = *(const float4*)(Ag);
  float4 pa1 = *(const float4*)(Ag + 64 * 256);
  float4 pb0 = *(const float4*)(Bg);
  float4 pb1 = *(const float4*)(Bg + 64 * 256);

  for (int kt = 0; kt < 16; ++kt) {
    __syncthreads();  // previous-iteration LDS reads done
    As_s[(lk * 4 + 0) * 132 + lr] = pa0.x; As_s[(lk * 4 + 1) * 132 + lr] = pa0.y;
    As_s[(lk * 4 + 2) * 132 + lr] = pa0.z; As_s[(lk * 4 + 3) * 132 + lr] = pa0.w;
    As_s[(lk * 4 + 0) * 132 + 64 + lr] = pa1.x; As_s[(lk * 4 + 1) * 132 + 64 + lr] = pa1.y;
    As_s[(lk * 4 + 2) * 132 + 64 + lr] = pa1.z; As_s[(lk * 4 + 3) * 132 + 64 + lr] = pa1.w;
    Bs_s[(lk * 4 + 0) * 132 + lr] = pb0.x; Bs_s[(lk * 4 + 1) * 132 + lr] = pb0.y;
    Bs_s[(lk * 4 + 2) * 132 + lr] = pb0.z; Bs_s[(lk * 4 + 3) * 132 + lr] = pb0.w;
    Bs_s[(lk * 4 + 0) * 132 + 64 + lr] = pb1.x; Bs_s[(lk * 4 + 1) * 132 + 64 + lr] = pb1.y;
    Bs_s[(lk * 4 + 2) * 132 + 64 + lr] = pb1.z; Bs_s[(lk * 4 + 3) * 132 + 64 + lr] = pb1.w;
    __syncthreads();
    // prefetch next K-tile (issued before the FMA block; hides HBM/L2 latency)
    float4 na0 = pa0, na1 = pa1, nb0 = pb0, nb1 = pb1;
    if (kt < 15) {
      const float* Ap = Ag + (kt + 1) * 16;
      const float* Bp = Bg + (kt + 1) * 16;
      na0 = *(const float4*)(Ap);
      na1 = *(const float4*)(Ap + 64 * 256);
      nb0 = *(const float4*)(Bp);
      nb1 = *(const float4*)(Bp + 64 * 256);
    }
#pragma unroll
    for (int kk = 0; kk < 16; ++kk) {
      float4 A0 = As4[kk][tm];
      float4 A1 = As4[kk][16 + tm];
      float4 B0 = Bs4[kk][tn];
      float4 B1 = Bs4[kk][16 + tn];
      MK(c000, c001, A0.x) MK(c010, c011, A0.y)
      MK(c020, c021, A0.z) MK(c030, c031, A0.w)
      MK(c100, c101, A1.x) MK(c110, c111, A1.y)
      MK(c120, c121, A1.z) MK(c130, c131, A1.w)
    }
    pa0 = na0; pa1 = na1; pb0 = nb0; pb1 = nb1;
  }
  // epilogue: d = ||x||^2 - 2 x.e + ||e||^2, store + per-row argmin partial
  float4 ep0 = *(const float4*)(esq + bn * 128 + tn * 4);
  float4 ep1 = *(const float4*)(esq + bn * 128 + 64 + tn * 4);
  EPI(0, 0, c000, c001) EPI(0, 1, c010, c011)
  EPI(0, 2, c020, c021) EPI(0, 3, c030, c031)
  EPI(1, 0, c100, c101) EPI(1, 1, c110, c111)
  EPI(1, 2, c120, c121) EPI(1, 3, c130, c131)
}

// ---- final argmin over 32 column-block partials; indices + histogram ----
// pval/pidx layout [block][token] -> coalesced reads here
__global__ __launch_bounds__(256) void k_argmin(const float* __restrict__ pval,
                                                const int* __restrict__ pidx,
                                                int* __restrict__ idxArr,
                                                float* __restrict__ outIdx,
                                                int* __restrict__ hist) {
  int t = blockIdx.x * 256 + TID;
  float bv = 3.4e38f; int bc = 0;
#pragma unroll
  for (int b = 0; b < 32; ++b) {  // ascending col blocks => strict < keeps lowest idx
    float v = pval[(long long)b * 32768 + t];
    if (v < bv) { bv = v; bc = pidx[(long long)b * 32768 + t]; }
  }
  idxArr[t] = bc;
  outIdx[t] = (float)bc;
  atomicAdd(&hist[bc], 1);
}

// ---- one-hot writer: zeros + the 1.0, single 512 MB pass (replaces memset+scatter) ----
__global__ __launch_bounds__(256) void k_onehot(const int* __restrict__ idxArr,
                                                float* __restrict__ enc) {
  int t0 = blockIdx.x * 8;
  float4 z = make_float4(0.f, 0.f, 0.f, 0.f);
#pragma unroll
  for (int r = 0; r < 8; ++r) {
    int t = t0 + r;
    int id = idxArr[t];
    float* p = enc + (long long)t * 4096 + TID * 16;
    *(float4*)(p + 0) = z; *(float4*)(p + 4) = z;
    *(float4*)(p + 8) = z; *(float4*)(p + 12) = z;
    if ((id >> 4) == TID) p[id & 15] = 1.0f;  // same thread -> ordered after zeros
  }
}

// ---- quantized gather -> NCHW output + loss partial ----
__global__ __launch_bounds__(256) void k_quant(const float* __restrict__ in,
                                               const float* __restrict__ emb,
                                               const int* __restrict__ idxArr,
                                               float* __restrict__ outQ,
                                               float* __restrict__ lossAcc) {
  __shared__ float q[32][257];
  __shared__ float ls[4];
  int b = blockIdx.x, n = b >> 5, h = b & 31;
  for (int w = 0; w < 32; ++w) {
    int id = idxArr[(n * 32 + w) * 32 + h];
    q[w][TID] = emb[(long long)id * 256 + TID];
  }
  __syncthreads();
  float sum = 0.f;
  int w = TID & 31, c8 = TID >> 5;
  const float* xin = in + (long long)n * 262144 + h * 32;
  float* xout = outQ + (long long)n * 262144 + h * 32;
#pragma unroll
  for (int p = 0; p < 32; ++p) {
    int c = p * 8 + c8;
    float qa = q[w][c];
    float xv = xin[c * 1024 + w];
    float d = qa - xv;
    sum += d * d;
    xout[c * 1024 + w] = qa;
  }
#pragma unroll
  for (int o = 32; o; o >>= 1) sum += __shfl_down(sum, o);
  if ((TID & 63) == 0) ls[TID >> 6] = sum;
  __syncthreads();
  if (TID == 0) atomicAdd(lossAcc, ls[0] + ls[1] + ls[2] + ls[3]);
}

// ---- loss + perplexity ----
__global__ __launch_bounds__(256) void k_final(const int* __restrict__ hist,
                                               const float* __restrict__ lossAcc,
                                               float* __restrict__ outLoss,
                                               float* __restrict__ outPerp) {
  __shared__ float ls[4];
  float s = 0.f;
  for (int k = TID; k < 4096; k += 256) {
    float p = (float)hist[k] * (1.0f / 32768.0f);
    s += p * logf(p + 1e-10f);
  }
#pragma unroll
  for (int o = 32; o; o >>= 1) s += __shfl_down(s, o);
  if ((TID & 63) == 0) ls[TID >> 6] = s;
  __syncthreads();
  if (TID == 0) {
    // forward value: q_latent_loss == e_latent_loss == mean((q-x)^2)
    *outLoss = lossAcc[0] * (1.25f / 8388608.0f);
    *outPerp = expf(-(ls[0] + ls[1] + ls[2] + ls[3]));
  }
}

extern "C" void kernel_launch(void* const* d_in, const int* in_sizes, int n_in,
                              void* d_out, int out_size, void* d_ws, size_t ws_size,
                              hipStream_t stream) {
  const float* inputs = (const float*)d_in[0];
  const float* emb = (const float*)d_in[1];
  float* out = (float*)d_out;
  float* ws = (float*)d_ws;

  // ws layout (floats): [0] lossAcc, [64..] hist(4096 int), [8192..] xsq(32768),
  // [40960..] esq(4096), [45056..] idxArr(32768 int)
  float* lossAcc = ws;
  int* hist = (int*)(ws + 64);
  float* xsq = ws + 8192;
  float* esq = ws + 40960;
  int* idxArr = (int*)(ws + 45056);

  float* flat = out + SCR_FLAT;            // scratch in encodings region
  float* pval = out + SCR_PVAL;
  int* pidx = (int*)(out + SCR_PIDX);
  float* dist = out + OFF_DIST;
  float* enc = out + OFF_ENC;

  hipMemsetAsync(d_ws, 0, 8192 * 4, stream);            // lossAcc + hist
  k_transpose<<<1024, 256, 0, stream>>>(inputs, flat);
  k_rowsq<<<8192, 256, 0, stream>>>(flat, xsq, 32768);
  k_rowsq<<<1024, 256, 0, stream>>>(emb, esq, 4096);
  k_gemm<<<8192, 256, 0, stream>>>(flat, emb, xsq, esq, dist, pval, pidx);
  k_argmin<<<128, 256, 0, stream>>>(pval, pidx, idxArr, out + OFF_IDX, hist);
  k_onehot<<<4096, 256, 0, stream>>>(idxArr, enc);      // zeros + 1.0 in one pass
  k_quant<<<1024, 256, 0, stream>>>(inputs, emb, idxArr, out, lossAcc);
  k_final<<<1, 256, 0, stream>>>(hist, lossAcc, out + OFF_LOSS, out + OFF_PERP);
}

// Round 3
// 1741.787 us; speedup vs baseline: 1.1490x; 1.1490x over previous
//
#include <hip/hip_runtime.h>
#include <math.h>

// Problem constants
constexpr int NB = 32, HH = 32, WW = 32, CD = 256, NK = 4096;
constexpr int T_ = NB * WW * HH;                       // 32768 tokens
constexpr long long NQ = (long long)NB * CD * HH * WW; // 8388608
constexpr long long OFF_LOSS = NQ;
constexpr long long OFF_PERP = NQ + 1;
constexpr long long OFF_ENC  = NQ + 2;                    // 8388610
constexpr long long ENC_SZ   = (long long)T_ * NK;        // 134217728
constexpr long long OFF_IDX  = OFF_ENC + ENC_SZ;          // 142606338
constexpr long long OFF_DIST = OFF_IDX + T_;              // 142639106
// scratch inside encodings output region (dead before k_onehot overwrites it)
constexpr long long SCR0    = 8388612;                    // 16B-aligned byte offset
constexpr long long O_APK   = SCR0;                       // f16 packed X: 32768*1024B (as floats: 8388608)
constexpr long long O_EPK   = SCR0 + 8388608;             // f16 packed E: 4096*1024B (1048576 floats)
constexpr long long O_FLAT  = O_EPK + 1048576;            // fp32 flat X: 8388608 floats
constexpr long long O_PVAL  = O_FLAT + 8388608;           // 64*32768 floats
constexpr long long O_PIDX  = O_PVAL + 2097152;           // 64*32768 ints
constexpr long long O_FLAGS = O_PIDX + 2097152;           // 32768 ints

#define TID ((int)threadIdx.x)

typedef _Float16 f16x8 __attribute__((ext_vector_type(8)));
typedef _Float16 f16x4v __attribute__((ext_vector_type(4)));
typedef float f32x4 __attribute__((ext_vector_type(4)));

// ---- NCHW -> [T,C]: fp32 flat + f16 hi/lo packed (8 chunks of 16B per 32-k group) ----
__global__ __launch_bounds__(256) void k_pack_x(const float* __restrict__ in,
                                                float* __restrict__ flat,
                                                char* __restrict__ apk) {
  __shared__ float t[256][33];
  int b = blockIdx.x, n = b >> 5, h = b & 31;
  int w = TID & 31, c8 = TID >> 5;
  const float* src = in + (long long)n * 262144 + h * 32;  // + c*1024 + w
#pragma unroll
  for (int p = 0; p < 32; ++p) {
    int c = p * 8 + c8;
    t[c][w] = src[c * 1024 + w];
  }
  __syncthreads();
  int c = TID;
  long long trow = (long long)n * 1024 + h;   // token = n*1024 + w2*32 + h
#pragma unroll
  for (int w2 = 0; w2 < 32; ++w2) {
    long long ti = trow + w2 * 32;
    float v = t[c][w2];
    flat[ti * 256 + c] = v;
    _Float16 hi = (_Float16)v;
    _Float16 lo = (_Float16)(v - (float)hi);
    char* pb = apk + ti * 1024 + ((c >> 5) << 7) + ((c & 31) << 1);
    *(_Float16*)pb = hi;
    *(_Float16*)(pb + 64) = lo;
  }
}

// ---- embeddings -> f16 packed + esq (one wave per row) ----
__global__ __launch_bounds__(256) void k_pack_e(const float* __restrict__ emb,
                                                char* __restrict__ epk,
                                                float* __restrict__ esq) {
  int row = blockIdx.x * 4 + (TID >> 6);
  int l = TID & 63;
  float4 v = *(const float4*)(emb + (long long)row * 256 + l * 4);
  f16x4v hi, lo;
  hi[0] = (_Float16)v.x; lo[0] = (_Float16)(v.x - (float)hi[0]);
  hi[1] = (_Float16)v.y; lo[1] = (_Float16)(v.y - (float)hi[1]);
  hi[2] = (_Float16)v.z; lo[2] = (_Float16)(v.z - (float)hi[2]);
  hi[3] = (_Float16)v.w; lo[3] = (_Float16)(v.w - (float)hi[3]);
  char* pb = epk + (long long)row * 1024 + ((l >> 3) << 7) + ((l & 7) << 3);
  *(f16x4v*)pb = hi;
  *(f16x4v*)(pb + 64) = lo;
  float s = v.x * v.x + v.y * v.y + v.z * v.z + v.w * v.w;
#pragma unroll
  for (int o = 32; o; o >>= 1) s += __shfl_down(s, o);
  if (l == 0) esq[row] = s;
}

// ---- per-row squared L2 norm of flat X ----
__global__ __launch_bounds__(256) void k_rowsq(const float* __restrict__ src,
                                               float* __restrict__ dst, int nrows) {
  int row = blockIdx.x * 4 + (TID >> 6);
  if (row >= nrows) return;
  int lane = TID & 63;
  float4 v = *(const float4*)(src + (long long)row * 256 + lane * 4);
  float s = v.x * v.x + v.y * v.y + v.z * v.z + v.w * v.w;
#pragma unroll
  for (int o = 32; o; o >>= 1) s += __shfl_down(s, o);
  if (lane == 0) dst[row] = s;
}

// ---- f16 2-split MFMA distance GEMM, 128x128 tile, BK=32, fused argmin partials ----
// LDS row = 128B (hi 4x16B | lo 4x16B), XOR swizzle slot^=(row&7); staged via
// global_load_lds with inverse-swizzled global source (linear LDS dest).
__global__ __launch_bounds__(256) void k_gemm(const char* __restrict__ apk,
                                              const char* __restrict__ epk,
                                              const float* __restrict__ xsq,
                                              const float* __restrict__ esq,
                                              float* __restrict__ dist,
                                              float* __restrict__ pval,
                                              int* __restrict__ pidx) {
  __shared__ char As[16384];
  __shared__ char Bs[16384];
  int bm = blockIdx.x >> 5, bn = blockIdx.x & 31;
  int wid = TID >> 6, l = TID & 63;
  int wm = wid >> 1, wn = wid & 1;
  int kg = l >> 4;

  f32x4 acc[4][4];
#pragma unroll
  for (int i = 0; i < 4; ++i)
#pragma unroll
    for (int j = 0; j < 4; ++j) acc[i][j] = (f32x4){0.f, 0.f, 0.f, 0.f};

  const char* srcBase = (wid < 2) ? (apk + (long long)bm * 128 * 1024)
                                  : (epk + (long long)bn * 128 * 1024);
  char* ldsBase = (wid < 2) ? As : Bs;
  int rpart = (wid & 1) * 64;
  int chunk = (l & 7) ^ ((l >> 3) & 7);   // inverse swizzle on source

  for (int kt = 0; kt < 8; ++kt) {
#pragma unroll
    for (int j = 0; j < 8; ++j) {
      int rl = rpart + j * 8 + (l >> 3);
      const char* src = srcBase + (long long)rl * 1024 + kt * 128 + chunk * 16;
      char* dst = ldsBase + (rpart + j * 8) * 128;   // wave-uniform
      __builtin_amdgcn_global_load_lds(
          (const __attribute__((address_space(1))) void*)src,
          (__attribute__((address_space(3))) void*)dst, 16, 0, 0);
    }
    __syncthreads();
    f16x8 ah[4], al[4], bh[4], bl[4];
#pragma unroll
    for (int mf = 0; mf < 4; ++mf) {
      int r = wm * 64 + mf * 16 + (l & 15);
      ah[mf] = *(const f16x8*)(As + r * 128 + ((kg ^ (r & 7)) << 4));
      al[mf] = *(const f16x8*)(As + r * 128 + (((kg + 4) ^ (r & 7)) << 4));
    }
#pragma unroll
    for (int nf = 0; nf < 4; ++nf) {
      int r = wn * 64 + nf * 16 + (l & 15);
      bh[nf] = *(const f16x8*)(Bs + r * 128 + ((kg ^ (r & 7)) << 4));
      bl[nf] = *(const f16x8*)(Bs + r * 128 + (((kg + 4) ^ (r & 7)) << 4));
    }
#pragma unroll
    for (int mf = 0; mf < 4; ++mf)
#pragma unroll
      for (int nf = 0; nf < 4; ++nf) {
        acc[mf][nf] = __builtin_amdgcn_mfma_f32_16x16x32_f16(ah[mf], bh[nf], acc[mf][nf], 0, 0, 0);
        acc[mf][nf] = __builtin_amdgcn_mfma_f32_16x16x32_f16(ah[mf], bl[nf], acc[mf][nf], 0, 0, 0);
        acc[mf][nf] = __builtin_amdgcn_mfma_f32_16x16x32_f16(al[mf], bh[nf], acc[mf][nf], 0, 0, 0);
      }
    __syncthreads();
  }

  // epilogue: d = ||x||^2 - 2 x.e + ||e||^2 ; C/D layout: col=l&15, row=(l>>4)*4+r
  float es[4];
#pragma unroll
  for (int nf = 0; nf < 4; ++nf) es[nf] = esq[bn * 128 + wn * 64 + nf * 16 + (l & 15)];
  int rowbase = bm * 128 + wm * 64;
  long long pblk = bn * 2 + wn;
#pragma unroll
  for (int mf = 0; mf < 4; ++mf) {
    float4 x4 = *(const float4*)(xsq + rowbase + mf * 16 + kg * 4);
    float xr[4] = {x4.x, x4.y, x4.z, x4.w};
#pragma unroll
    for (int r = 0; r < 4; ++r) {
      int row = rowbase + mf * 16 + kg * 4 + r;
      float xs = xr[r];
      float bv = 3.4e38f; int bc = 0;
#pragma unroll
      for (int nf = 0; nf < 4; ++nf) {   // nf ascending => lowest col on ties
        float v = xs - 2.0f * acc[mf][nf][r] + es[nf];
        dist[(long long)row * 4096 + bn * 128 + wn * 64 + nf * 16 + (l & 15)] = v;
        if (v < bv) { bv = v; bc = nf; }
      }
      int col = bn * 128 + wn * 64 + bc * 16 + (l & 15);
#pragma unroll
      for (int m = 1; m < 16; m <<= 1) {
        float ov = __shfl_xor(bv, m);
        int oc = __shfl_xor(col, m);
        if (ov < bv || (ov == bv && oc < col)) { bv = ov; col = oc; }
      }
      if ((l & 15) == 0) {
        pval[pblk * 32768 + row] = bv;
        pidx[pblk * 32768 + row] = col;
      }
    }
  }
}

// ---- argmin over 64 col-block partials + near-tie flagging ----
__global__ __launch_bounds__(256) void k_argmin(const float* __restrict__ pval,
                                                const int* __restrict__ pidx,
                                                int* __restrict__ idxArr,
                                                int* __restrict__ flags,
                                                int* __restrict__ nflag) {
  int t = blockIdx.x * 256 + TID;
  float bv = 3.4e38f, sec = 3.4e38f; int bc = 0;
#pragma unroll
  for (int b = 0; b < 64; ++b) {   // ascending col blocks => strict < keeps lowest idx
    float v = pval[(long long)b * 32768 + t];
    if (v < bv) { sec = bv; bv = v; bc = pidx[(long long)b * 32768 + t]; }
    else if (v < sec) sec = v;
  }
  idxArr[t] = bc;
  if (sec - bv < 0.125f) {   // MFMA-precision guard band
    int p = atomicAdd(nflag, 1);
    flags[p] = t;
  }
}

// ---- exact fp32 argmin recompute for flagged tokens ----
__global__ __launch_bounds__(256) void k_fixup(const float* __restrict__ flat,
                                               const float* __restrict__ emb,
                                               const float* __restrict__ xsq,
                                               const float* __restrict__ esq,
                                               const int* __restrict__ flags,
                                               const int* __restrict__ nflag,
                                               int* __restrict__ idxArr) {
  __shared__ float xrow[256];
  __shared__ float rv[256];
  __shared__ int rk[256];
  int nf = *nflag;
  for (int f = blockIdx.x; f < nf; f += 256) {
    __syncthreads();
    int t = flags[f];
    xrow[TID] = flat[(long long)t * 256 + TID];
    __syncthreads();
    float xs = xsq[t];
    float bv = 3.4e38f; int bk = 1 << 30;
    for (int j = 0; j < 16; ++j) {
      int k = j * 256 + TID;
      const float* er = emb + (long long)k * 256;
      float dot = 0.f;
      for (int c = 0; c < 256; ++c) dot = fmaf(xrow[c], er[c], dot);
      float v = xs - 2.0f * dot + esq[k];
      if (v < bv || (v == bv && k < bk)) { bv = v; bk = k; }
    }
    rv[TID] = bv; rk[TID] = bk;
    __syncthreads();
    for (int s = 128; s; s >>= 1) {
      if (TID < s) {
        float ov = rv[TID + s]; int ok = rk[TID + s];
        if (ov < rv[TID] || (ov == rv[TID] && ok < rk[TID])) { rv[TID] = ov; rk[TID] = ok; }
      }
      __syncthreads();
    }
    if (TID == 0) idxArr[t] = rk[0];
  }
}

// ---- histogram + float indices (post-fixup) ----
__global__ __launch_bounds__(256) void k_hist(const int* __restrict__ idxArr,
                                              float* __restrict__ outIdx,
                                              int* __restrict__ hist) {
  int t = blockIdx.x * 256 + TID;
  int id = idxArr[t];
  outIdx[t] = (float)id;
  atomicAdd(&hist[id], 1);
}

// ---- one-hot writer, wave-per-row, fully coalesced 1KB stores ----
__global__ __launch_bounds__(256) void k_onehot(const int* __restrict__ idxArr,
                                                float* __restrict__ enc) {
  int t = blockIdx.x * 4 + (TID >> 6);
  int lane = TID & 63;
  int id = idxArr[t];
  float* row = enc + (long long)t * 4096;
#pragma unroll
  for (int j = 0; j < 16; ++j) {
    int pos = j * 256 + lane * 4;
    float4 z = make_float4(0.f, 0.f, 0.f, 0.f);
    int d = id - pos;
    if (d >= 0 && d < 4) ((float*)&z)[d] = 1.0f;
    *(float4*)(row + pos) = z;
  }
}

// ---- quantized gather -> NCHW output + loss partial ----
__global__ __launch_bounds__(256) void k_quant(const float* __restrict__ in,
                                               const float* __restrict__ emb,
                                               const int* __restrict__ idxArr,
                                               float* __restrict__ outQ,
                                               float* __restrict__ lossAcc) {
  __shared__ float q[32][257];
  __shared__ float ls[4];
  int b = blockIdx.x, n = b >> 5, h = b & 31;
  for (int w = 0; w < 32; ++w) {
    int id = idxArr[(n * 32 + w) * 32 + h];
    q[w][TID] = emb[(long long)id * 256 + TID];
  }
  __syncthreads();
  float sum = 0.f;
  int w = TID & 31, c8 = TID >> 5;
  const float* xin = in + (long long)n * 262144 + h * 32;
  float* xout = outQ + (long long)n * 262144 + h * 32;
#pragma unroll
  for (int p = 0; p < 32; ++p) {
    int c = p * 8 + c8;
    float qa = q[w][c];
    float xv = xin[c * 1024 + w];
    float d = qa - xv;
    sum += d * d;
    xout[c * 1024 + w] = qa;
  }
#pragma unroll
  for (int o = 32; o; o >>= 1) sum += __shfl_down(sum, o);
  if ((TID & 63) == 0) ls[TID >> 6] = sum;
  __syncthreads();
  if (TID == 0) atomicAdd(lossAcc, ls[0] + ls[1] + ls[2] + ls[3]);
}

// ---- loss + perplexity ----
__global__ __launch_bounds__(256) void k_final(const int* __restrict__ hist,
                                               const float* __restrict__ lossAcc,
                                               float* __restrict__ outLoss,
                                               float* __restrict__ outPerp) {
  __shared__ float ls[4];
  float s = 0.f;
  for (int k = TID; k < 4096; k += 256) {
    float p = (float)hist[k] * (1.0f / 32768.0f);
    s += p * logf(p + 1e-10f);
  }
#pragma unroll
  for (int o = 32; o; o >>= 1) s += __shfl_down(s, o);
  if ((TID & 63) == 0) ls[TID >> 6] = s;
  __syncthreads();
  if (TID == 0) {
    *outLoss = lossAcc[0] * (1.25f / 8388608.0f);
    *outPerp = expf(-(ls[0] + ls[1] + ls[2] + ls[3]));
  }
}

extern "C" void kernel_launch(void* const* d_in, const int* in_sizes, int n_in,
                              void* d_out, int out_size, void* d_ws, size_t ws_size,
                              hipStream_t stream) {
  const float* inputs = (const float*)d_in[0];
  const float* emb = (const float*)d_in[1];
  float* out = (float*)d_out;
  float* ws = (float*)d_ws;

  // ws layout (floats): [0] lossAcc, [1] nflag(int), [64..] hist(4096 int),
  // [8192..] xsq(32768), [40960..] esq(4096), [45056..] idxArr(32768 int)
  float* lossAcc = ws;
  int* nflag = (int*)(ws + 1);
  int* hist = (int*)(ws + 64);
  float* xsq = ws + 8192;
  float* esq = ws + 40960;
  int* idxArr = (int*)(ws + 45056);

  char* apk = (char*)(out + O_APK);
  char* epk = (char*)(out + O_EPK);
  float* flat = out + O_FLAT;
  float* pval = out + O_PVAL;
  int* pidx = (int*)(out + O_PIDX);
  int* flags = (int*)(out + O_FLAGS);
  float* dist = out + OFF_DIST;
  float* enc = out + OFF_ENC;

  hipMemsetAsync(d_ws, 0, 32768, stream);               // lossAcc + nflag + hist
  k_pack_x<<<1024, 256, 0, stream>>>(inputs, flat, apk);
  k_pack_e<<<1024, 256, 0, stream>>>(emb, epk, esq);
  k_rowsq<<<8192, 256, 0, stream>>>(flat, xsq, 32768);
  k_gemm<<<8192, 256, 0, stream>>>(apk, epk, xsq, esq, dist, pval, pidx);
  k_argmin<<<128, 256, 0, stream>>>(pval, pidx, idxArr, flags, nflag);
  k_fixup<<<256, 256, 0, stream>>>(flat, emb, xsq, esq, flags, nflag, idxArr);
  k_hist<<<128, 256, 0, stream>>>(idxArr, out + OFF_IDX, hist);
  k_onehot<<<8192, 256, 0, stream>>>(idxArr, enc);
  k_quant<<<1024, 256, 0, stream>>>(inputs, emb, idxArr, out, lossAcc);
  k_final<<<1, 256, 0, stream>>>(hist, lossAcc, out + OFF_LOSS, out + OFF_PERP);
}